// Round 1
// baseline (759.528 us; speedup 1.0000x reference)
//
#include <hip/hip_runtime.h>

// ---------------- helpers ----------------
typedef __attribute__((ext_vector_type(8))) short bf16x8;   // 8 bf16 = 4 VGPRs
typedef __attribute__((ext_vector_type(4))) float f32x4;

__device__ __forceinline__ float bf2f(unsigned short b) {
    unsigned u = ((unsigned)b) << 16; float f;
    __builtin_memcpy(&f, &u, 4); return f;
}
__device__ __forceinline__ unsigned short f2bf(float f) {
    unsigned u; __builtin_memcpy(&u, &f, 4);
    unsigned r = u + 0x7FFFu + ((u >> 16) & 1u);   // RNE
    return (unsigned short)(r >> 16);
}

__device__ __forceinline__ void async_copy16(const unsigned short* g, unsigned short* l) {
    __builtin_amdgcn_global_load_lds(
        (const __attribute__((address_space(1))) unsigned int*)g,
        (__attribute__((address_space(3))) unsigned int*)l, 16, 0, 0);
}

#define EPI_F32 0
#define EPI_RELU_BF16 1
#define EPI_ROTARY 2

// ---------------- bf16 GEMM: C[M,N] = A[M,K](lda) @ B^T[N,K] ----------------
// 128x128 tile, BK=32, 256 threads = 4 waves (2x2 of 64x64), 16x16x32 MFMA.
template <int EPI>
__global__ __launch_bounds__(256) void gemm_bt(
    const unsigned short* __restrict__ A, int lda,
    const unsigned short* __restrict__ B, int K, int N,
    float* __restrict__ Cf, unsigned short* __restrict__ Cb,
    const float* __restrict__ pe,
    unsigned short* __restrict__ out_elu,
    unsigned short* __restrict__ out_pos,
    unsigned short* __restrict__ out_vrot)
{
    __shared__ unsigned short Asm[128 * 32];
    __shared__ unsigned short Bsm[128 * 32];
    const int t = threadIdx.x;
    const int lane = t & 63, w = t >> 6;
    const int wm = w & 1, wn = w >> 1;
    const int quad = lane >> 4, low = lane & 15;
    const int m0 = blockIdx.x * 128, n0 = blockIdx.y * 128;

    f32x4 acc[4][4];
#pragma unroll
    for (int i = 0; i < 4; i++)
#pragma unroll
        for (int j = 0; j < 4; j++) acc[i][j] = (f32x4){0.f, 0.f, 0.f, 0.f};

    for (int k0 = 0; k0 < K; k0 += 32) {
        __syncthreads();
#pragma unroll
        for (int i = 0; i < 2; i++) {
            const int chunk = i * 256 + t;
            const int row = chunk >> 2, part = chunk & 3;
            async_copy16(A + (size_t)(m0 + row) * lda + k0 + part * 8,
                         Asm + (i * 256 + w * 64) * 8);
            async_copy16(B + (size_t)(n0 + row) * K + k0 + part * 8,
                         Bsm + (i * 256 + w * 64) * 8);
        }
        __syncthreads();
        bf16x8 a[4], b[4];
#pragma unroll
        for (int mi = 0; mi < 4; mi++)
            a[mi] = *(const bf16x8*)&Asm[(wm * 64 + mi * 16 + low) * 32 + quad * 8];
#pragma unroll
        for (int ni = 0; ni < 4; ni++)
            b[ni] = *(const bf16x8*)&Bsm[(wn * 64 + ni * 16 + low) * 32 + quad * 8];
#pragma unroll
        for (int mi = 0; mi < 4; mi++)
#pragma unroll
            for (int ni = 0; ni < 4; ni++)
                acc[mi][ni] = __builtin_amdgcn_mfma_f32_16x16x32_bf16(a[mi], b[ni], acc[mi][ni], 0, 0, 0);
    }

    const int gmb = m0 + wm * 64, gnb = n0 + wn * 64;
#pragma unroll
    for (int mi = 0; mi < 4; mi++)
#pragma unroll
        for (int ni = 0; ni < 4; ni++)
#pragma unroll
            for (int r = 0; r < 4; r++) {
                const int row = gmb + mi * 16 + quad * 4 + r;
                const int col = gnb + ni * 16 + low;
                float v = acc[mi][ni][r];
                if constexpr (EPI == EPI_F32) {
                    Cf[(size_t)row * N + col] = v;
                } else if constexpr (EPI == EPI_RELU_BF16) {
                    Cb[(size_t)row * N + col] = f2bf(v > 0.f ? v : 0.f);
                } else {
                    const float p = __shfl_xor(v, 1);       // value at col^1, same row
                    const int c = col & 255;
                    const float2 cs = *(const float2*)&pe[((size_t)row * 256 + c) * 2];
                    const float x2 = (c & 1) ? p : -p;       // rotate-pair term
                    const unsigned short rot = f2bf(v * cs.x + x2 * cs.y);
                    if (col < 256) {
                        out_elu[(size_t)row * 256 + c] = f2bf(v > 0.f ? v + 1.f : __expf(v));
                        out_pos[(size_t)row * 256 + c] = rot;
                    } else {
                        out_vrot[(size_t)row * 256 + c] = rot;
                    }
                }
            }
}

// ---------------- weight transpose fp32 -> bf16: WT[n*K+k] = W[k*N+n] ----------------
__global__ void transp_bf16(const float* __restrict__ W, unsigned short* __restrict__ WT, int K, int N) {
    const int idx = blockIdx.x * 256 + threadIdx.x;
    if (idx >= K * N) return;
    const int n = idx / K, k = idx - n * K;
    WT[idx] = f2bf(W[(size_t)k * N + n]);
}

// ---------------- fp32 [rows,256] -> bf16 with dst row-stride ----------------
__global__ void conv_bf16(const float* __restrict__ src, unsigned short* __restrict__ dst, int dstride) {
    const int idx = blockIdx.x * 256 + threadIdx.x;  // one per 4 elems
    const int row = idx >> 6;
    const int c0 = (idx & 63) * 4;
    const float4 v = *(const float4*)&src[(size_t)row * 256 + c0];
    unsigned short o[4] = {f2bf(v.x), f2bf(v.y), f2bf(v.z), f2bf(v.w)};
    *(uint2*)&dst[(size_t)row * dstride + c0] = *(const uint2*)o;
}

// ---------------- Ksum[n][c] = sum_s Kelu[n,s,c] ----------------
__global__ void ksum_kernel(const unsigned short* __restrict__ Kelu, float* __restrict__ Ksum) {
    const int n = blockIdx.x, chunk = blockIdx.y, c = threadIdx.x;
    float s = 0.f;
    const size_t base = ((size_t)(n * 4096 + chunk * 128)) * 256 + c;
    for (int i = 0; i < 128; i++) s += bf2f(Kelu[base + (size_t)i * 256]);
    atomicAdd(&Ksum[n * 256 + c], s);
}

// ---------------- KVT[n][h][v][d] += sum_s Kpos[n,s,h,d]*Vrot[n,s,h,v] ----------------
__global__ __launch_bounds__(256) void kv_kernel(const unsigned short* __restrict__ Kpos,
                                                 const unsigned short* __restrict__ Vrot,
                                                 float* __restrict__ KVT) {
    const int n = blockIdx.x, h = blockIdx.y, sc = blockIdx.z;
    const int t = threadIdx.x;
    __shared__ unsigned short kb[64 * 32];
    __shared__ unsigned short vb[64 * 32];
    const int d = t >> 3, v0 = (t & 7) * 4;
    const int sl = t >> 2, p = (t & 3) * 8;
    float a0 = 0.f, a1 = 0.f, a2 = 0.f, a3 = 0.f;
    for (int ss = 0; ss < 512; ss += 64) {
        __syncthreads();
        const size_t row = (size_t)(n * 4096 + sc * 512 + ss + sl);
        *(uint4*)&kb[sl * 32 + p] = *(const uint4*)&Kpos[row * 256 + h * 32 + p];
        *(uint4*)&vb[sl * 32 + p] = *(const uint4*)&Vrot[row * 256 + h * 32 + p];
        __syncthreads();
        for (int s = 0; s < 64; s++) {
            const float kk = bf2f(kb[s * 32 + d]);
            uint2 vv = *(const uint2*)&vb[s * 32 + v0];
            const unsigned short* pv = (const unsigned short*)&vv;
            a0 += kk * bf2f(pv[0]); a1 += kk * bf2f(pv[1]);
            a2 += kk * bf2f(pv[2]); a3 += kk * bf2f(pv[3]);
        }
    }
    const size_t b = (((size_t)n * 8 + h) * 32) * 32 + d;
    atomicAdd(&KVT[b + (size_t)(v0 + 0) * 32], a0);
    atomicAdd(&KVT[b + (size_t)(v0 + 1) * 32], a1);
    atomicAdd(&KVT[b + (size_t)(v0 + 2) * 32], a2);
    atomicAdd(&KVT[b + (size_t)(v0 + 3) * 32], a3);
}

// ---------------- queried[row][c] = Z * sum_d Qpos[row,h,d] * KV[n,h,d,v] ----------------
__global__ __launch_bounds__(256) void queried_kernel(
    const unsigned short* __restrict__ Qelu, const unsigned short* __restrict__ Qpos,
    const float* __restrict__ KVT, const float* __restrict__ Ksum,
    unsigned short* __restrict__ Qout)
{
    const int chunk = blockIdx.x, n = blockIdx.y;
    const int t = threadIdx.x;
    __shared__ float kvs[8 * 32 * 36];   // padded stride 36 (bank spread, 16B aligned)
    __shared__ float ks[256];
    __shared__ float qps[256];
    for (int i = t; i < 8192; i += 256) {
        const int h = i >> 10, v = (i >> 5) & 31, d = i & 31;
        kvs[h * 1152 + v * 36 + d] = KVT[(size_t)n * 8192 + i];
    }
    ks[t] = Ksum[n * 256 + t];
    const int h = t >> 5, v = t & 31;
    const float* kvh = &kvs[h * 1152 + v * 36];
    const float* qph = &qps[h * 32];
    for (int r = 0; r < 128; r++) {
        const size_t row = (size_t)n * 4096 + chunk * 128 + r;
        const float qe = bf2f(Qelu[row * 256 + t]);
        const float qp = bf2f(Qpos[row * 256 + t]);
        __syncthreads();              // prev-iter qps reads done; kvs staged (r=0)
        qps[t] = qp;
        float ps = qe * ks[t];
#pragma unroll
        for (int off = 1; off < 32; off <<= 1) ps += __shfl_xor(ps, off);
        const float Z = 1.f / (ps + 1e-6f);
        __syncthreads();              // qps visible
        float s = 0.f;
#pragma unroll
        for (int d4 = 0; d4 < 32; d4 += 4) {
            const float4 qa = *(const float4*)&qph[d4];
            const float4 ka = *(const float4*)&kvh[d4];
            s += qa.x * ka.x + qa.y * ka.y + qa.z * ka.z + qa.w * ka.w;
        }
        Qout[row * 256 + t] = f2bf(s * Z);
    }
}

// ---------------- LayerNorms ----------------
__global__ void ln1_kernel(const float* __restrict__ msg, unsigned short* __restrict__ a2,
                           const float* __restrict__ g, const float* __restrict__ b) {
    const int row = blockIdx.x, t = threadIdx.x;
    const float v = msg[(size_t)row * 256 + t];
    float s1 = v, s2 = v * v;
#pragma unroll
    for (int off = 32; off >= 1; off >>= 1) { s1 += __shfl_xor(s1, off); s2 += __shfl_xor(s2, off); }
    __shared__ float red[8];
    const int w = t >> 6;
    if ((t & 63) == 0) { red[w * 2] = s1; red[w * 2 + 1] = s2; }
    __syncthreads();
    s1 = red[0] + red[2] + red[4] + red[6];
    s2 = red[1] + red[3] + red[5] + red[7];
    const float mean = s1 * (1.f / 256.f);
    const float var = s2 * (1.f / 256.f) - mean * mean;
    const float rstd = rsqrtf(var + 1e-5f);
    a2[(size_t)row * 512 + 256 + t] = f2bf((v - mean) * rstd * g[t] + b[t]);
}

__global__ void ln2_res_kernel(const float* __restrict__ msg, const float* __restrict__ x,
                               const float* __restrict__ g, const float* __restrict__ b,
                               float* __restrict__ out) {
    const int row = blockIdx.x, t = threadIdx.x;
    const float v = msg[(size_t)row * 256 + t];
    float s1 = v, s2 = v * v;
#pragma unroll
    for (int off = 32; off >= 1; off >>= 1) { s1 += __shfl_xor(s1, off); s2 += __shfl_xor(s2, off); }
    __shared__ float red[8];
    const int w = t >> 6;
    if ((t & 63) == 0) { red[w * 2] = s1; red[w * 2 + 1] = s2; }
    __syncthreads();
    s1 = red[0] + red[2] + red[4] + red[6];
    s2 = red[1] + red[3] + red[5] + red[7];
    const float mean = s1 * (1.f / 256.f);
    const float var = s2 * (1.f / 256.f) - mean * mean;
    const float rstd = rsqrtf(var + 1e-5f);
    out[(size_t)row * 256 + t] = x[(size_t)row * 256 + t] + (v - mean) * rstd * g[t] + b[t];
}

// ---------------- launch ----------------
extern "C" void kernel_launch(void* const* d_in, const int* in_sizes, int n_in,
                              void* d_out, int out_size, void* d_ws, size_t ws_size,
                              hipStream_t stream) {
    const float* x   = (const float*)d_in[0];
    const float* src = (const float*)d_in[1];
    const float* xpe = (const float*)d_in[2];
    const float* spe = (const float*)d_in[3];
    const float* Wq  = (const float*)d_in[4];
    const float* Wk  = (const float*)d_in[5];
    const float* Wv  = (const float*)d_in[6];
    const float* Wm  = (const float*)d_in[7];
    const float* W1  = (const float*)d_in[8];
    const float* W2  = (const float*)d_in[9];
    const float* g1  = (const float*)d_in[10];
    const float* b1  = (const float*)d_in[11];
    const float* g2  = (const float*)d_in[12];
    const float* b2  = (const float*)d_in[13];

    char* p = (char*)d_ws;
    unsigned short* WqT  = (unsigned short*)p; p += 256 * 256 * 2;
    unsigned short* WkvT = (unsigned short*)p; p += 512 * 256 * 2;
    unsigned short* WmT  = (unsigned short*)p; p += 256 * 256 * 2;
    unsigned short* W1T  = (unsigned short*)p; p += 512 * 512 * 2;
    unsigned short* W2T  = (unsigned short*)p; p += 256 * 512 * 2;
    float* KVT  = (float*)p; p += 8 * 8 * 32 * 32 * 4;
    float* Ksum = (float*)p; p += 8 * 256 * 4;
    unsigned short* A2   = (unsigned short*)p; p += (size_t)32768 * 512 * 2;  // cols 0-255: x, 256-511: LN1(msg)
    unsigned short* srcB = (unsigned short*)p; p += (size_t)32768 * 256 * 2;
    unsigned short* Qelu = (unsigned short*)p; p += (size_t)32768 * 256 * 2;
    unsigned short* Qpos = (unsigned short*)p; p += (size_t)32768 * 256 * 2;
    unsigned short* Kelu = (unsigned short*)p; p += (size_t)32768 * 256 * 2;
    unsigned short* Kpos = (unsigned short*)p; p += (size_t)32768 * 256 * 2;
    unsigned short* Vrot = (unsigned short*)p; p += (size_t)32768 * 256 * 2;
    unsigned short* Qrd  = (unsigned short*)p; p += (size_t)32768 * 256 * 2;
    // safe aliases (dependency-ordered):
    float* msg1 = (float*)Kelu;                 // 32MB over Kelu+Kpos (dead after kv/ksum)
    unsigned short* hbuf = (unsigned short*)Qelu; // 32MB over Qelu+Qpos (dead after queried)
    float* msg2 = (float*)Vrot;                 // 32MB over Vrot+Qrd (dead after Wm GEMM)

    hipMemsetAsync(KVT, 0, 8 * 8 * 32 * 32 * 4 + 8 * 256 * 4, stream);

    transp_bf16<<<256, 256, 0, stream>>>(Wq, WqT, 256, 256);
    transp_bf16<<<256, 256, 0, stream>>>(Wk, WkvT, 256, 256);
    transp_bf16<<<256, 256, 0, stream>>>(Wv, WkvT + 256 * 256, 256, 256);
    transp_bf16<<<256, 256, 0, stream>>>(Wm, WmT, 256, 256);
    transp_bf16<<<1024, 256, 0, stream>>>(W1, W1T, 512, 512);
    transp_bf16<<<512, 256, 0, stream>>>(W2, W2T, 512, 256);
    conv_bf16<<<8192, 256, 0, stream>>>(x, A2, 512);
    conv_bf16<<<8192, 256, 0, stream>>>(src, srcB, 256);

    // projections + fused elu/rotary epilogues
    gemm_bt<EPI_ROTARY><<<dim3(256, 2), 256, 0, stream>>>(A2, 512, WqT, 256, 256,
        nullptr, nullptr, xpe, Qelu, Qpos, Qpos);
    gemm_bt<EPI_ROTARY><<<dim3(256, 4), 256, 0, stream>>>(srcB, 256, WkvT, 256, 512,
        nullptr, nullptr, spe, Kelu, Kpos, Vrot);

    ksum_kernel<<<dim3(8, 32), 256, 0, stream>>>(Kelu, Ksum);
    kv_kernel<<<dim3(8, 8, 8), 256, 0, stream>>>(Kpos, Vrot, KVT);
    queried_kernel<<<dim3(32, 8), 256, 0, stream>>>(Qelu, Qpos, KVT, Ksum, Qrd);

    gemm_bt<EPI_F32><<<dim3(256, 2), 256, 0, stream>>>(Qrd, 256, WmT, 256, 256,
        msg1, nullptr, nullptr, nullptr, nullptr, nullptr);
    ln1_kernel<<<32768, 256, 0, stream>>>(msg1, A2, g1, b1);
    gemm_bt<EPI_RELU_BF16><<<dim3(256, 4), 256, 0, stream>>>(A2, 512, W1T, 512, 512,
        nullptr, hbuf, nullptr, nullptr, nullptr, nullptr);
    gemm_bt<EPI_F32><<<dim3(256, 2), 256, 0, stream>>>(hbuf, 512, W2T, 512, 256,
        msg2, nullptr, nullptr, nullptr, nullptr, nullptr);
    ln2_res_kernel<<<32768, 256, 0, stream>>>(msg2, x, g2, b2, (float*)d_out);
}

// Round 2
// 457.776 us; speedup vs baseline: 1.6592x; 1.6592x over previous
//
#include <hip/hip_runtime.h>

// ---------------- helpers ----------------
typedef __attribute__((ext_vector_type(8))) short bf16x8;   // 8 bf16 = 4 VGPRs
typedef __attribute__((ext_vector_type(4))) float f32x4;

__device__ __forceinline__ float bf2f(unsigned short b) {
    unsigned u = ((unsigned)b) << 16; float f;
    __builtin_memcpy(&f, &u, 4); return f;
}
__device__ __forceinline__ unsigned short f2bf(float f) {
    unsigned u; __builtin_memcpy(&u, &f, 4);
    unsigned r = u + 0x7FFFu + ((u >> 16) & 1u);   // RNE
    return (unsigned short)(r >> 16);
}

__device__ __forceinline__ void async_copy16(const unsigned short* g, unsigned short* l) {
    __builtin_amdgcn_global_load_lds(
        (const __attribute__((address_space(1))) unsigned int*)g,
        (__attribute__((address_space(3))) unsigned int*)l, 16, 0, 0);
}

#define EPI_F32 0
#define EPI_RELU_BF16 1
#define EPI_ROTARY_Q 2
#define EPI_ROTARY_KV 3

// ---------------- bf16 GEMM: C[M,N] = A[M,K](lda) @ B^T[N,K] ----------------
// 128x128 tile, BK=32, 256 threads = 4 waves (2x2 of 64x64), 16x16x32 MFMA.
template <int EPI>
__global__ __launch_bounds__(256) void gemm_bt(
    const unsigned short* __restrict__ A, int lda,
    const unsigned short* __restrict__ B, int K, int N,
    float* __restrict__ Cf, unsigned short* __restrict__ Cb,
    const float* __restrict__ pe,
    const float* __restrict__ Ksum, float* __restrict__ Zbuf,
    unsigned short* __restrict__ out_pos,       // Qpos natural [row][c]
    unsigned short* __restrict__ outT_k,        // KposT [(n*256+c)][s]
    unsigned short* __restrict__ outT_v,        // VrotT [(n*256+c)][s]
    unsigned short* __restrict__ out_elu)       // Kelu natural [row][c]
{
    __shared__ unsigned short Asm[128 * 32];
    __shared__ unsigned short Bsm[128 * 32];
    const int t = threadIdx.x;
    const int lane = t & 63, w = t >> 6;
    const int wm = w & 1, wn = w >> 1;
    const int quad = lane >> 4, low = lane & 15;
    const int m0 = blockIdx.x * 128, n0 = blockIdx.y * 128;

    f32x4 acc[4][4];
#pragma unroll
    for (int i = 0; i < 4; i++)
#pragma unroll
        for (int j = 0; j < 4; j++) acc[i][j] = (f32x4){0.f, 0.f, 0.f, 0.f};

    for (int k0 = 0; k0 < K; k0 += 32) {
        __syncthreads();
#pragma unroll
        for (int i = 0; i < 2; i++) {
            const int chunk = i * 256 + t;
            const int row = chunk >> 2, part = chunk & 3;
            async_copy16(A + (size_t)(m0 + row) * lda + k0 + part * 8,
                         Asm + (i * 256 + w * 64) * 8);
            async_copy16(B + (size_t)(n0 + row) * K + k0 + part * 8,
                         Bsm + (i * 256 + w * 64) * 8);
        }
        __syncthreads();
        bf16x8 a[4], b[4];
#pragma unroll
        for (int mi = 0; mi < 4; mi++)
            a[mi] = *(const bf16x8*)&Asm[(wm * 64 + mi * 16 + low) * 32 + quad * 8];
#pragma unroll
        for (int ni = 0; ni < 4; ni++)
            b[ni] = *(const bf16x8*)&Bsm[(wn * 64 + ni * 16 + low) * 32 + quad * 8];
#pragma unroll
        for (int mi = 0; mi < 4; mi++)
#pragma unroll
            for (int ni = 0; ni < 4; ni++)
                acc[mi][ni] = __builtin_amdgcn_mfma_f32_16x16x32_bf16(a[mi], b[ni], acc[mi][ni], 0, 0, 0);
    }

    const int gmb = m0 + wm * 64, gnb = n0 + wn * 64;

    if constexpr (EPI == EPI_F32) {
#pragma unroll
        for (int mi = 0; mi < 4; mi++)
#pragma unroll
            for (int ni = 0; ni < 4; ni++)
#pragma unroll
                for (int r = 0; r < 4; r++) {
                    const int row = gmb + mi * 16 + quad * 4 + r;
                    const int col = gnb + ni * 16 + low;
                    Cf[(size_t)row * N + col] = acc[mi][ni][r];
                }
    } else if constexpr (EPI == EPI_RELU_BF16) {
#pragma unroll
        for (int mi = 0; mi < 4; mi++)
#pragma unroll
            for (int ni = 0; ni < 4; ni++)
#pragma unroll
                for (int r = 0; r < 4; r++) {
                    const int row = gmb + mi * 16 + quad * 4 + r;
                    const int col = gnb + ni * 16 + low;
                    const float v = acc[mi][ni][r];
                    Cb[(size_t)row * N + col] = f2bf(v > 0.f ? v : 0.f);
                }
    } else if constexpr (EPI == EPI_ROTARY_Q) {
        // N=256. Writes Qpos + per-(row,head) Z = 1/(sum_d elu1(q)*Ksum + eps).
#pragma unroll
        for (int mi = 0; mi < 4; mi++) {
#pragma unroll
            for (int j = 0; j < 2; j++) {
                float zp[4] = {0.f, 0.f, 0.f, 0.f};
#pragma unroll
                for (int nn = 0; nn < 2; nn++) {
                    const int ni = j * 2 + nn;
                    const int c = gnb + ni * 16 + low;
#pragma unroll
                    for (int r = 0; r < 4; r++) {
                        const int row = gmb + mi * 16 + quad * 4 + r;
                        const float v = acc[mi][ni][r];
                        const float pp = __shfl_xor(v, 1);
                        const float2 cs = *(const float2*)&pe[((size_t)row * 256 + c) * 2];
                        const float x2 = (c & 1) ? pp : -pp;
                        out_pos[(size_t)row * 256 + c] = f2bf(v * cs.x + x2 * cs.y);
                        const float e = (v > 0.f ? v + 1.f : __expf(v)) * Ksum[(row >> 12) * 256 + c];
                        zp[r] += e;
                    }
                }
#pragma unroll
                for (int r = 0; r < 4; r++) {
                    float s = zp[r];
                    s += __shfl_xor(s, 1); s += __shfl_xor(s, 2);
                    s += __shfl_xor(s, 4); s += __shfl_xor(s, 8);
                    if (low == 0) {
                        const int row = gmb + mi * 16 + quad * 4 + r;
                        Zbuf[(size_t)row * 8 + ((gnb + j * 32) >> 5)] = 1.f / (s + 1e-6f);
                    }
                }
            }
        }
    } else {  // EPI_ROTARY_KV: cols 0-255 -> Kelu natural + KposT; 256-511 -> VrotT
#pragma unroll
        for (int mi = 0; mi < 4; mi++) {
            const int row0 = gmb + mi * 16 + quad * 4;
            const int n = row0 >> 12, s = row0 & 4095;
#pragma unroll
            for (int ni = 0; ni < 4; ni++) {
                const int colg = gnb + ni * 16 + low;
                const int c = colg & 255;
                unsigned short rpack[4];
#pragma unroll
                for (int r = 0; r < 4; r++) {
                    const int row = row0 + r;
                    const float v = acc[mi][ni][r];
                    const float pp = __shfl_xor(v, 1);
                    const float2 cs = *(const float2*)&pe[((size_t)row * 256 + c) * 2];
                    const float x2 = (c & 1) ? pp : -pp;
                    rpack[r] = f2bf(v * cs.x + x2 * cs.y);
                    if (colg < 256)
                        out_elu[(size_t)row * 256 + c] = f2bf(v > 0.f ? v + 1.f : __expf(v));
                }
                unsigned short* dT = (colg < 256) ? outT_k : outT_v;
                *(uint2*)&dT[((size_t)(n * 256 + c)) * 4096 + s] = *(const uint2*)rpack;
            }
        }
    }
}

// ---------------- weight transpose fp32 -> bf16: WT[n*K+k] = W[k*N+n] ----------------
__global__ void transp_bf16(const float* __restrict__ W, unsigned short* __restrict__ WT, int K, int N) {
    const int idx = blockIdx.x * 256 + threadIdx.x;
    if (idx >= K * N) return;
    const int n = idx / K, k = idx - n * K;
    WT[idx] = f2bf(W[(size_t)k * N + n]);
}

// ---------------- fp32 [rows,256] -> bf16 with dst row-stride ----------------
__global__ void conv_bf16(const float* __restrict__ src, unsigned short* __restrict__ dst, int dstride) {
    const int idx = blockIdx.x * 256 + threadIdx.x;  // one per 4 elems
    const int row = idx >> 6;
    const int c0 = (idx & 63) * 4;
    const float4 v = *(const float4*)&src[(size_t)row * 256 + c0];
    unsigned short o[4] = {f2bf(v.x), f2bf(v.y), f2bf(v.z), f2bf(v.w)};
    *(uint2*)&dst[(size_t)row * dstride + c0] = *(const uint2*)o;
}

// ---------------- Ksum[n][c] = sum_s Kelu[n,s,c] ----------------
__global__ void ksum_kernel(const unsigned short* __restrict__ Kelu, float* __restrict__ Ksum) {
    const int n = blockIdx.x, chunk = blockIdx.y, c = threadIdx.x;
    float s = 0.f;
    const size_t base = ((size_t)(n * 4096 + chunk * 128)) * 256 + c;
    for (int i = 0; i < 128; i++) s += bf2f(Kelu[base + (size_t)i * 256]);
    atomicAdd(&Ksum[n * 256 + c], s);
}

// ---------------- KV via MFMA: KVT[n][h][v][d] = sum_s KposT[nh,d,s]*VrotT[nh,v,s] ----------------
// grid (64, 4): block = (n,h) x s-chunk of 1024; wave w handles 256 s.
__global__ __launch_bounds__(256) void kv2_kernel(const unsigned short* __restrict__ KposT,
                                                  const unsigned short* __restrict__ VrotT,
                                                  float* __restrict__ KVT) {
    const int nh = blockIdx.x, sc = blockIdx.y;
    const int t = threadIdx.x, lane = t & 63, w = t >> 6;
    const int quad = lane >> 4, low = lane & 15;
    const unsigned short* Abase = KposT + (size_t)nh * 32 * 4096;
    const unsigned short* Bbase = VrotT + (size_t)nh * 32 * 4096;
    const int sbase = sc * 1024 + w * 256;

    f32x4 acc[2][2];
#pragma unroll
    for (int i = 0; i < 2; i++)
#pragma unroll
        for (int j = 0; j < 2; j++) acc[i][j] = (f32x4){0.f, 0.f, 0.f, 0.f};

    for (int s0 = 0; s0 < 256; s0 += 32) {
        const int sk = sbase + s0 + quad * 8;
        bf16x8 a[2], b[2];
#pragma unroll
        for (int mi = 0; mi < 2; mi++)
            a[mi] = *(const bf16x8*)&Abase[(size_t)(mi * 16 + low) * 4096 + sk];
#pragma unroll
        for (int ni = 0; ni < 2; ni++)
            b[ni] = *(const bf16x8*)&Bbase[(size_t)(ni * 16 + low) * 4096 + sk];
#pragma unroll
        for (int mi = 0; mi < 2; mi++)
#pragma unroll
            for (int ni = 0; ni < 2; ni++)
                acc[mi][ni] = __builtin_amdgcn_mfma_f32_16x16x32_bf16(a[mi], b[ni], acc[mi][ni], 0, 0, 0);
    }

    __shared__ float red[4][1024];   // [wave][d*32+v]
#pragma unroll
    for (int mi = 0; mi < 2; mi++)
#pragma unroll
        for (int ni = 0; ni < 2; ni++)
#pragma unroll
            for (int r = 0; r < 4; r++)
                red[w][(mi * 16 + quad * 4 + r) * 32 + ni * 16 + low] = acc[mi][ni][r];
    __syncthreads();
#pragma unroll
    for (int k = 0; k < 4; k++) {
        const int i = t + k * 256;
        const float s = red[0][i] + red[1][i] + red[2][i] + red[3][i];
        atomicAdd(&KVT[(size_t)nh * 1024 + (size_t)(i & 31) * 32 + (i >> 5)], s);  // [v][d]
    }
}

// ---------------- queried = (Qpos @ KV[h]) * Z : M=32768, N=32, K=32 per head ----------------
// grid (128, 8): 256 rows per block, head = blockIdx.y.
__global__ __launch_bounds__(256) void attn_out_kernel(const unsigned short* __restrict__ Qpos,
                                                       const float* __restrict__ KVT,
                                                       const float* __restrict__ Zbuf,
                                                       unsigned short* __restrict__ Qrd) {
    const int h = blockIdx.y, mt = blockIdx.x;
    const int t = threadIdx.x, lane = t & 63, w = t >> 6;
    const int quad = lane >> 4, low = lane & 15;
    const int rbase = mt * 256 + w * 64;
    const int n = rbase >> 12;

    bf16x8 b[2];
#pragma unroll
    for (int ni = 0; ni < 2; ni++) {
        const float* src = &KVT[((size_t)(n * 8 + h) * 32 + ni * 16 + low) * 32 + quad * 8];
        short tmp[8];
#pragma unroll
        for (int j = 0; j < 8; j++) tmp[j] = (short)f2bf(src[j]);
        __builtin_memcpy(&b[ni], tmp, 16);
    }

    f32x4 acc[4][2];
#pragma unroll
    for (int i = 0; i < 4; i++)
#pragma unroll
        for (int j = 0; j < 2; j++) acc[i][j] = (f32x4){0.f, 0.f, 0.f, 0.f};

#pragma unroll
    for (int mi = 0; mi < 4; mi++) {
        const bf16x8 a = *(const bf16x8*)&Qpos[((size_t)(rbase + mi * 16 + low)) * 256 + h * 32 + quad * 8];
#pragma unroll
        for (int ni = 0; ni < 2; ni++)
            acc[mi][ni] = __builtin_amdgcn_mfma_f32_16x16x32_bf16(a, b[ni], acc[mi][ni], 0, 0, 0);
    }

#pragma unroll
    for (int mi = 0; mi < 4; mi++)
#pragma unroll
        for (int ni = 0; ni < 2; ni++)
#pragma unroll
            for (int r = 0; r < 4; r++) {
                const int row = rbase + mi * 16 + quad * 4 + r;
                const int col = h * 32 + ni * 16 + low;
                Qrd[(size_t)row * 256 + col] = f2bf(acc[mi][ni][r] * Zbuf[(size_t)row * 8 + h]);
            }
}

// ---------------- LayerNorms ----------------
__global__ void ln1_kernel(const float* __restrict__ msg, unsigned short* __restrict__ a2,
                           const float* __restrict__ g, const float* __restrict__ b) {
    const int row = blockIdx.x, t = threadIdx.x;
    const float v = msg[(size_t)row * 256 + t];
    float s1 = v, s2 = v * v;
#pragma unroll
    for (int off = 32; off >= 1; off >>= 1) { s1 += __shfl_xor(s1, off); s2 += __shfl_xor(s2, off); }
    __shared__ float red[8];
    const int w = t >> 6;
    if ((t & 63) == 0) { red[w * 2] = s1; red[w * 2 + 1] = s2; }
    __syncthreads();
    s1 = red[0] + red[2] + red[4] + red[6];
    s2 = red[1] + red[3] + red[5] + red[7];
    const float mean = s1 * (1.f / 256.f);
    const float var = s2 * (1.f / 256.f) - mean * mean;
    const float rstd = rsqrtf(var + 1e-5f);
    a2[(size_t)row * 512 + 256 + t] = f2bf((v - mean) * rstd * g[t] + b[t]);
}

__global__ void ln2_res_kernel(const float* __restrict__ msg, const float* __restrict__ x,
                               const float* __restrict__ g, const float* __restrict__ b,
                               float* __restrict__ out) {
    const int row = blockIdx.x, t = threadIdx.x;
    const float v = msg[(size_t)row * 256 + t];
    float s1 = v, s2 = v * v;
#pragma unroll
    for (int off = 32; off >= 1; off >>= 1) { s1 += __shfl_xor(s1, off); s2 += __shfl_xor(s2, off); }
    __shared__ float red[8];
    const int w = t >> 6;
    if ((t & 63) == 0) { red[w * 2] = s1; red[w * 2 + 1] = s2; }
    __syncthreads();
    s1 = red[0] + red[2] + red[4] + red[6];
    s2 = red[1] + red[3] + red[5] + red[7];
    const float mean = s1 * (1.f / 256.f);
    const float var = s2 * (1.f / 256.f) - mean * mean;
    const float rstd = rsqrtf(var + 1e-5f);
    out[(size_t)row * 256 + t] = x[(size_t)row * 256 + t] + (v - mean) * rstd * g[t] + b[t];
}

// ---------------- launch ----------------
extern "C" void kernel_launch(void* const* d_in, const int* in_sizes, int n_in,
                              void* d_out, int out_size, void* d_ws, size_t ws_size,
                              hipStream_t stream) {
    const float* x   = (const float*)d_in[0];
    const float* src = (const float*)d_in[1];
    const float* xpe = (const float*)d_in[2];
    const float* spe = (const float*)d_in[3];
    const float* Wq  = (const float*)d_in[4];
    const float* Wk  = (const float*)d_in[5];
    const float* Wv  = (const float*)d_in[6];
    const float* Wm  = (const float*)d_in[7];
    const float* W1  = (const float*)d_in[8];
    const float* W2  = (const float*)d_in[9];
    const float* g1  = (const float*)d_in[10];
    const float* b1  = (const float*)d_in[11];
    const float* g2  = (const float*)d_in[12];
    const float* b2  = (const float*)d_in[13];

    char* p = (char*)d_ws;
    unsigned short* WqT  = (unsigned short*)p; p += 256 * 256 * 2;
    unsigned short* WkvT = (unsigned short*)p; p += 512 * 256 * 2;
    unsigned short* WmT  = (unsigned short*)p; p += 256 * 256 * 2;
    unsigned short* W1T  = (unsigned short*)p; p += 512 * 512 * 2;
    unsigned short* W2T  = (unsigned short*)p; p += 256 * 512 * 2;
    float* KVT  = (float*)p; p += 64 * 1024 * 4;
    float* Ksum = (float*)p; p += 8 * 256 * 4;
    float* Zbuf = (float*)p; p += (size_t)32768 * 8 * 4;
    unsigned short* A2   = (unsigned short*)p; p += (size_t)32768 * 512 * 2;  // cols 0-255: x, 256-511: LN1(msg)
    unsigned short* srcB = (unsigned short*)p; p += (size_t)32768 * 256 * 2;
    unsigned short* Kelu  = (unsigned short*)p; p += (size_t)32768 * 256 * 2;
    unsigned short* KposT = (unsigned short*)p; p += (size_t)32768 * 256 * 2;
    unsigned short* VrotT = (unsigned short*)p; p += (size_t)32768 * 256 * 2;
    unsigned short* Qpos  = (unsigned short*)p; p += (size_t)32768 * 256 * 2;
    unsigned short* Qrd   = (unsigned short*)p; p += (size_t)32768 * 256 * 2;
    // aliases (stream-ordered lifetimes):
    float* msg1 = (float*)Kelu;                   // 32MB over Kelu+KposT (dead after ksum/kv2)
    unsigned short* hbuf = (unsigned short*)VrotT; // 32MB over VrotT+Qpos (dead after kv2/attn)
    float* msg2 = msg1;                            // msg1 dead after ln1

    hipMemsetAsync(KVT, 0, 64 * 1024 * 4 + 8 * 256 * 4, stream);

    transp_bf16<<<256, 256, 0, stream>>>(Wq, WqT, 256, 256);
    transp_bf16<<<256, 256, 0, stream>>>(Wk, WkvT, 256, 256);
    transp_bf16<<<256, 256, 0, stream>>>(Wv, WkvT + 256 * 256, 256, 256);
    transp_bf16<<<256, 256, 0, stream>>>(Wm, WmT, 256, 256);
    transp_bf16<<<1024, 256, 0, stream>>>(W1, W1T, 512, 512);
    transp_bf16<<<512, 256, 0, stream>>>(W2, W2T, 512, 256);
    conv_bf16<<<8192, 256, 0, stream>>>(x, A2, 512);
    conv_bf16<<<8192, 256, 0, stream>>>(src, srcB, 256);

    // K/V projection + rotary/elu epilogue (writes Kelu natural, KposT/VrotT transposed)
    gemm_bt<EPI_ROTARY_KV><<<dim3(256, 4), 256, 0, stream>>>(srcB, 256, WkvT, 256, 512,
        nullptr, nullptr, spe, nullptr, nullptr, nullptr, KposT, VrotT, Kelu);
    ksum_kernel<<<dim3(8, 32), 256, 0, stream>>>(Kelu, Ksum);
    // Q projection + rotary epilogue + fused Z (needs Ksum)
    gemm_bt<EPI_ROTARY_Q><<<dim3(256, 2), 256, 0, stream>>>(A2, 512, WqT, 256, 256,
        nullptr, nullptr, xpe, Ksum, Zbuf, Qpos, nullptr, nullptr, nullptr);

    kv2_kernel<<<dim3(64, 4), 256, 0, stream>>>(KposT, VrotT, KVT);
    attn_out_kernel<<<dim3(128, 8), 256, 0, stream>>>(Qpos, KVT, Zbuf, Qrd);

    gemm_bt<EPI_F32><<<dim3(256, 2), 256, 0, stream>>>(Qrd, 256, WmT, 256, 256,
        msg1, nullptr, nullptr, nullptr, nullptr, nullptr, nullptr, nullptr, nullptr);
    ln1_kernel<<<32768, 256, 0, stream>>>(msg1, A2, g1, b1);
    gemm_bt<EPI_RELU_BF16><<<dim3(256, 4), 256, 0, stream>>>(A2, 512, W1T, 512, 512,
        nullptr, hbuf, nullptr, nullptr, nullptr, nullptr, nullptr, nullptr, nullptr);
    gemm_bt<EPI_F32><<<dim3(256, 2), 256, 0, stream>>>(hbuf, 512, W2T, 512, 256,
        msg2, nullptr, nullptr, nullptr, nullptr, nullptr, nullptr, nullptr, nullptr);
    ln2_res_kernel<<<32768, 256, 0, stream>>>(msg2, x, g2, b2, (float*)d_out);
}

// Round 4
// 406.708 us; speedup vs baseline: 1.8675x; 1.1256x over previous
//
#include <hip/hip_runtime.h>

// ---------------- helpers ----------------
typedef __attribute__((ext_vector_type(8))) short bf16x8;   // 8 bf16 = 4 VGPRs
typedef __attribute__((ext_vector_type(4))) float f32x4;

__device__ __forceinline__ float bf2f(unsigned short b) {
    unsigned u = ((unsigned)b) << 16; float f;
    __builtin_memcpy(&f, &u, 4); return f;
}
__device__ __forceinline__ unsigned short f2bf(float f) {
    unsigned u; __builtin_memcpy(&u, &f, 4);
    unsigned r = u + 0x7FFFu + ((u >> 16) & 1u);   // RNE
    return (unsigned short)(r >> 16);
}
__device__ __forceinline__ unsigned packbf(float a, float b) {
    return (unsigned)f2bf(a) | ((unsigned)f2bf(b) << 16);
}
__device__ __forceinline__ float elu1(float v) { return v > 0.f ? v + 1.f : __expf(v); }

__device__ __forceinline__ void async_copy16(const unsigned short* g, unsigned short* l) {
    __builtin_amdgcn_global_load_lds(
        (const __attribute__((address_space(1))) unsigned int*)g,
        (__attribute__((address_space(3))) unsigned int*)l, 16, 0, 0);
}

// tile-col -> channel permutation: lane low holds channels (2*low, 2*low+1) in adjacent ni
__device__ __host__ __forceinline__ int chan_of(int tc) {
    return (tc & ~63) | ((tc & 15) << 1) | ((tc >> 4) & 1) | (((tc >> 5) & 1) << 5);
}
__device__ __forceinline__ int chan_even(int gnb, int p, int low) {
    const int tc = gnb + 32 * p + low;   // ni = 2p  (bit4 = 0)
    return (tc & ~63) | ((tc & 15) << 1) | (((tc >> 5) & 1) << 5);
}

#define EPI_RELU 0     // W1: relu, permuted pair store, natural hbuf
#define EPI_Q 1        // Wq: rotary + Z (needs Ksum), permuted
#define EPI_KV 2       // Wk|Wv: rotary + KF/VF frag store + Ksum atomics, permuted
#define EPI_LN1 3      // Wm: LN1 -> A2 cols 256-511, permuted
#define EPI_LN2RES 4   // W2: LN2 + residual -> d_out fp32, permuted

// ---------------- bf16 GEMM: C[M,N] = A[M,K](lda) @ B^T[N,K] ----------------
// MTxNT tile, BK=32, 256 threads = 4 waves (2x2), 16x16x32 MFMA.
template <int MT, int NT, int EPI>
__global__ __launch_bounds__(256) void gemm_bt(
    const unsigned short* __restrict__ A, int lda,
    const unsigned short* __restrict__ B, int K,
    unsigned short* __restrict__ Cb, int ldc,
    const float* __restrict__ pe,
    const float* __restrict__ KsumC, float* __restrict__ KsumA,
    float* __restrict__ Zbuf, unsigned short* __restrict__ Qpos,
    unsigned short* __restrict__ KF, unsigned short* __restrict__ VF,
    const float* __restrict__ g, const float* __restrict__ bta,
    unsigned short* __restrict__ A2out,
    const float* __restrict__ xres, float* __restrict__ outF)
{
    constexpr int WM = MT / 2, WN = NT / 2, MI = WM / 16, NI = WN / 16;
    __shared__ unsigned short Asm[MT * 32];
    __shared__ unsigned short Bsm[NT * 32];
    const int t = threadIdx.x;
    const int lane = t & 63, w = t >> 6;
    const int wm = w & 1, wn = w >> 1;
    const int quad = lane >> 4, low = lane & 15;
    const int m0 = blockIdx.x * MT, n0 = blockIdx.y * NT;

    f32x4 acc[MI][NI];
#pragma unroll
    for (int i = 0; i < MI; i++)
#pragma unroll
        for (int j = 0; j < NI; j++) acc[i][j] = (f32x4){0.f, 0.f, 0.f, 0.f};

    for (int k0 = 0; k0 < K; k0 += 32) {
        __syncthreads();
#pragma unroll
        for (int i = 0; i < MT / 64; i++) {
            const int chunk = i * 256 + t;
            const int row = chunk >> 2, part = chunk & 3;
            async_copy16(A + (size_t)(m0 + row) * lda + k0 + part * 8,
                         Asm + (i * 256 + w * 64) * 8);
        }
#pragma unroll
        for (int i = 0; i < NT / 64; i++) {
            const int chunk = i * 256 + t;
            const int row = chunk >> 2, part = chunk & 3;
            async_copy16(B + (size_t)(n0 + row) * K + k0 + part * 8,
                         Bsm + (i * 256 + w * 64) * 8);
        }
        __syncthreads();
        bf16x8 a[MI], b[NI];
#pragma unroll
        for (int mi = 0; mi < MI; mi++)
            a[mi] = *(const bf16x8*)&Asm[(wm * WM + mi * 16 + low) * 32 + quad * 8];
#pragma unroll
        for (int ni = 0; ni < NI; ni++)
            b[ni] = *(const bf16x8*)&Bsm[(wn * WN + ni * 16 + low) * 32 + quad * 8];
#pragma unroll
        for (int mi = 0; mi < MI; mi++)
#pragma unroll
            for (int ni = 0; ni < NI; ni++)
                acc[mi][ni] = __builtin_amdgcn_mfma_f32_16x16x32_bf16(a[mi], b[ni], acc[mi][ni], 0, 0, 0);
    }

    const int gmb = m0 + wm * WM, gnb = n0 + wn * WN;

    if constexpr (EPI == EPI_RELU) {
        // permuted pair store, output natural layout [row][ldc]
#pragma unroll
        for (int mi = 0; mi < MI; mi++)
#pragma unroll
            for (int p = 0; p < NI / 2; p++) {
                const int c_e = chan_even(gnb, p, low);
#pragma unroll
                for (int r = 0; r < 4; r++) {
                    const int row = gmb + mi * 16 + quad * 4 + r;
                    const float ve = acc[mi][2 * p][r], vo = acc[mi][2 * p + 1][r];
                    *(unsigned*)&Cb[(size_t)row * ldc + c_e] =
                        packbf(ve > 0.f ? ve : 0.f, vo > 0.f ? vo : 0.f);
                }
            }
    } else if constexpr (EPI == EPI_Q) {
        const int n = m0 >> 12;
#pragma unroll
        for (int p = 0; p < NI / 2; p++) {
            const int c_e = chan_even(gnb, p, low);
            const int head = c_e >> 5;
            const float2 ks = *(const float2*)&KsumC[n * 256 + c_e];
#pragma unroll
            for (int mi = 0; mi < MI; mi++) {
#pragma unroll
                for (int r = 0; r < 4; r++) {
                    const int row = gmb + mi * 16 + quad * 4 + r;
                    const float4 cs = *(const float4*)&pe[((size_t)row * 256 + c_e) * 2];
                    const float ve = acc[mi][2 * p][r], vo = acc[mi][2 * p + 1][r];
                    *(unsigned*)&Qpos[(size_t)row * 256 + c_e] =
                        packbf(ve * cs.x - vo * cs.y, vo * cs.z + ve * cs.w);
                    float z = elu1(ve) * ks.x + elu1(vo) * ks.y;
                    z += __shfl_xor(z, 1); z += __shfl_xor(z, 2);
                    z += __shfl_xor(z, 4); z += __shfl_xor(z, 8);
                    if (low == 0) Zbuf[(size_t)row * 8 + head] = 1.f / (z + 1e-6f);
                }
            }
        }
    } else if constexpr (EPI == EPI_KV) {
        const int n = m0 >> 12;
#pragma unroll
        for (int p = 0; p < NI / 2; p++) {
            const int c_full = chan_even(gnb, p, low);
            const bool isK = c_full < 256;
            const int c = c_full & 255;
            const int nh = n * 8 + (c >> 5), d = c & 31;
            unsigned short* dst = isK ? KF : VF;
            float kel_e = 0.f, kel_o = 0.f;
#pragma unroll
            for (int mi = 0; mi < MI; mi++) {
                const int row0 = gmb + mi * 16 + quad * 4;
                const int s0 = row0 & 4095;
                unsigned short pk[8];
#pragma unroll
                for (int r = 0; r < 4; r++) {
                    const int row = row0 + r;
                    const float4 cs = *(const float4*)&pe[((size_t)row * 256 + c) * 2];
                    const float ve = acc[mi][2 * p][r], vo = acc[mi][2 * p + 1][r];
                    pk[r]     = f2bf(ve * cs.x - vo * cs.y);
                    pk[4 + r] = f2bf(vo * cs.z + ve * cs.w);
                    if (isK) { kel_e += elu1(ve); kel_o += elu1(vo); }
                }
                const size_t base = ((size_t)nh * 512 + (s0 >> 3)) * 32;
                *(uint2*)&dst[(base + d) * 8 + (s0 & 7)]     = *(const uint2*)&pk[0];
                *(uint2*)&dst[(base + d + 1) * 8 + (s0 & 7)] = *(const uint2*)&pk[4];
            }
            if (isK) {
                kel_e += __shfl_xor(kel_e, 16); kel_e += __shfl_xor(kel_e, 32);
                kel_o += __shfl_xor(kel_o, 16); kel_o += __shfl_xor(kel_o, 32);
                if (quad == 0) {
                    atomicAdd(&KsumA[n * 256 + c], kel_e);
                    atomicAdd(&KsumA[n * 256 + c + 1], kel_o);
                }
            }
        }
    } else {  // EPI_LN1 / EPI_LN2RES  (MT=64, NT=256: block owns full rows)
        __shared__ float2 lnp[2][64];
        __syncthreads();   // all waves past last K-iter LDS traffic before lnp use
#pragma unroll
        for (int mi = 0; mi < MI; mi++)
#pragma unroll
            for (int r = 0; r < 4; r++) {
                float s1 = 0.f, s2 = 0.f;
#pragma unroll
                for (int ni = 0; ni < NI; ni++) {
                    const float v = acc[mi][ni][r];
                    s1 += v; s2 += v * v;
                }
                s1 += __shfl_xor(s1, 1); s2 += __shfl_xor(s2, 1);
                s1 += __shfl_xor(s1, 2); s2 += __shfl_xor(s2, 2);
                s1 += __shfl_xor(s1, 4); s2 += __shfl_xor(s2, 4);
                s1 += __shfl_xor(s1, 8); s2 += __shfl_xor(s2, 8);
                if (low == 0) lnp[wn][wm * WM + mi * 16 + quad * 4 + r] = make_float2(s1, s2);
            }
        __syncthreads();
#pragma unroll
        for (int mi = 0; mi < MI; mi++)
#pragma unroll
            for (int r = 0; r < 4; r++) {
                const int rl = wm * WM + mi * 16 + quad * 4 + r;
                const int row = m0 + rl;
                const float2 pa = lnp[0][rl], pb = lnp[1][rl];
                const float mean = (pa.x + pb.x) * (1.f / 256.f);
                const float var = (pa.y + pb.y) * (1.f / 256.f) - mean * mean;
                const float rstd = rsqrtf(var + 1e-5f);
#pragma unroll
                for (int p = 0; p < NI / 2; p++) {
                    const int c_e = chan_even(gnb, p, low);
                    const float2 gg = *(const float2*)&g[c_e];
                    const float2 bb = *(const float2*)&bta[c_e];
                    const float ve = acc[mi][2 * p][r], vo = acc[mi][2 * p + 1][r];
                    const float oe = (ve - mean) * rstd * gg.x + bb.x;
                    const float oo = (vo - mean) * rstd * gg.y + bb.y;
                    if constexpr (EPI == EPI_LN1) {
                        *(unsigned*)&A2out[(size_t)row * 512 + 256 + c_e] = packbf(oe, oo);
                    } else {
                        const float2 xv = *(const float2*)&xres[(size_t)row * 256 + c_e];
                        float2 o; o.x = xv.x + oe; o.y = xv.y + oo;
                        *(float2*)&outF[(size_t)row * 256 + c_e] = o;
                    }
                }
            }
    }
}

// ---------------- weight prep + workspace zeroing (replaces hipMemsetAsync) ----------------
// idx < 655360: weight transpose/permute/cast.  idx >= 655360: zero KVT+Ksum (67584 floats).
__global__ void prep_weights(const float* __restrict__ Wq, const float* __restrict__ Wk,
                             const float* __restrict__ Wv, const float* __restrict__ Wm,
                             const float* __restrict__ W1, const float* __restrict__ W2,
                             unsigned short* __restrict__ WqT, unsigned short* __restrict__ WkvT,
                             unsigned short* __restrict__ WmT, unsigned short* __restrict__ W1T,
                             unsigned short* __restrict__ W2T, float* __restrict__ zero_base) {
    const int idx = blockIdx.x * 256 + threadIdx.x;
    if (idx < 65536) {
        const int tc = idx >> 8, k = idx & 255;
        WqT[idx] = f2bf(Wq[(size_t)k * 256 + chan_of(tc)]);
    } else if (idx < 196608) {
        const int i = idx - 65536, tc = i >> 8, k = i & 255;
        const int c = chan_of(tc);
        WkvT[i] = f2bf(c < 256 ? Wk[(size_t)k * 256 + c] : Wv[(size_t)k * 256 + (c - 256)]);
    } else if (idx < 262144) {
        const int i = idx - 196608, tc = i >> 8, k = i & 255;
        WmT[i] = f2bf(Wm[(size_t)k * 256 + chan_of(tc)]);
    } else if (idx < 524288) {
        const int i = idx - 262144, tc = i >> 9, k = i & 511;
        W1T[i] = f2bf(W1[(size_t)k * 512 + chan_of(tc)]);
    } else if (idx < 655360) {
        const int i = idx - 524288, tc = i >> 9, k = i & 511;
        W2T[i] = f2bf(W2[(size_t)k * 256 + chan_of(tc)]);
    } else {
        zero_base[idx - 655360] = 0.f;   // KVT (65536) + Ksum (2048), contiguous
    }
}

// ---------------- fp32 [rows,256] -> bf16 with dst row-stride ----------------
__global__ void conv_bf16(const float* __restrict__ src, unsigned short* __restrict__ dst, int dstride) {
    const int idx = blockIdx.x * 256 + threadIdx.x;  // one per 4 elems
    const int row = idx >> 6;
    const int c0 = (idx & 63) * 4;
    const float4 v = *(const float4*)&src[(size_t)row * 256 + c0];
    unsigned short o[4] = {f2bf(v.x), f2bf(v.y), f2bf(v.z), f2bf(v.w)};
    *(uint2*)&dst[(size_t)row * dstride + c0] = *(const uint2*)o;
}

// ---------------- KV via MFMA from frag-major KF/VF: KVT[nh][v][d] ----------------
__global__ __launch_bounds__(256) void kv2_kernel(const unsigned short* __restrict__ KF,
                                                  const unsigned short* __restrict__ VF,
                                                  float* __restrict__ KVT) {
    const int nh = blockIdx.x, sc = blockIdx.y;
    const int t = threadIdx.x, lane = t & 63, w = t >> 6;
    const int quad = lane >> 4, low = lane & 15;
    const int sbase = sc * 1024 + w * 256;

    f32x4 acc[2][2];
#pragma unroll
    for (int i = 0; i < 2; i++)
#pragma unroll
        for (int j = 0; j < 2; j++) acc[i][j] = (f32x4){0.f, 0.f, 0.f, 0.f};

    for (int s0 = 0; s0 < 256; s0 += 32) {
        const int sk = sbase + s0 + quad * 8;
        const size_t cb = ((size_t)nh * 512 + (sk >> 3)) * 32;
        bf16x8 a[2], b[2];
#pragma unroll
        for (int mi = 0; mi < 2; mi++)
            a[mi] = *(const bf16x8*)&KF[(cb + mi * 16 + low) * 8];
#pragma unroll
        for (int ni = 0; ni < 2; ni++)
            b[ni] = *(const bf16x8*)&VF[(cb + ni * 16 + low) * 8];
#pragma unroll
        for (int mi = 0; mi < 2; mi++)
#pragma unroll
            for (int ni = 0; ni < 2; ni++)
                acc[mi][ni] = __builtin_amdgcn_mfma_f32_16x16x32_bf16(a[mi], b[ni], acc[mi][ni], 0, 0, 0);
    }

    __shared__ float red[4][1024];   // [wave][d*32+v]
#pragma unroll
    for (int mi = 0; mi < 2; mi++)
#pragma unroll
        for (int ni = 0; ni < 2; ni++)
#pragma unroll
            for (int r = 0; r < 4; r++)
                red[w][(mi * 16 + quad * 4 + r) * 32 + ni * 16 + low] = acc[mi][ni][r];
    __syncthreads();
#pragma unroll
    for (int k = 0; k < 4; k++) {
        const int i = t + k * 256;
        const float s = red[0][i] + red[1][i] + red[2][i] + red[3][i];
        atomicAdd(&KVT[(size_t)nh * 1024 + (size_t)(i & 31) * 32 + (i >> 5)], s);  // [v][d]
    }
}

// ---------------- queried = (Qpos @ KV[h]) * Z : M=32768, N=32, K=32 per head ----------------
__global__ __launch_bounds__(256) void attn_out_kernel(const unsigned short* __restrict__ Qpos,
                                                       const float* __restrict__ KVT,
                                                       const float* __restrict__ Zbuf,
                                                       unsigned short* __restrict__ Qrd) {
    const int h = blockIdx.y, mt = blockIdx.x;
    const int t = threadIdx.x, lane = t & 63, w = t >> 6;
    const int quad = lane >> 4, low = lane & 15;
    const int rbase = mt * 256 + w * 64;
    const int n = rbase >> 12;

    bf16x8 b[2];
#pragma unroll
    for (int ni = 0; ni < 2; ni++) {
        const float* src = &KVT[((size_t)(n * 8 + h) * 32 + ni * 16 + low) * 32 + quad * 8];
        short tmp[8];
#pragma unroll
        for (int j = 0; j < 8; j++) tmp[j] = (short)f2bf(src[j]);
        __builtin_memcpy(&b[ni], tmp, 16);
    }

    f32x4 acc[4][2];
#pragma unroll
    for (int i = 0; i < 4; i++)
#pragma unroll
        for (int j = 0; j < 2; j++) acc[i][j] = (f32x4){0.f, 0.f, 0.f, 0.f};

#pragma unroll
    for (int mi = 0; mi < 4; mi++) {
        const bf16x8 a = *(const bf16x8*)&Qpos[((size_t)(rbase + mi * 16 + low)) * 256 + h * 32 + quad * 8];
#pragma unroll
        for (int ni = 0; ni < 2; ni++)
            acc[mi][ni] = __builtin_amdgcn_mfma_f32_16x16x32_bf16(a, b[ni], acc[mi][ni], 0, 0, 0);
    }

#pragma unroll
    for (int mi = 0; mi < 4; mi++)
#pragma unroll
        for (int ni = 0; ni < 2; ni++)
#pragma unroll
            for (int r = 0; r < 4; r++) {
                const int row = rbase + mi * 16 + quad * 4 + r;
                const int col = h * 32 + ni * 16 + low;
                Qrd[(size_t)row * 256 + col] = f2bf(acc[mi][ni][r] * Zbuf[(size_t)row * 8 + h]);
            }
}

// ---------------- launch ----------------
extern "C" void kernel_launch(void* const* d_in, const int* in_sizes, int n_in,
                              void* d_out, int out_size, void* d_ws, size_t ws_size,
                              hipStream_t stream) {
    const float* x   = (const float*)d_in[0];
    const float* src = (const float*)d_in[1];
    const float* xpe = (const float*)d_in[2];
    const float* spe = (const float*)d_in[3];
    const float* Wq  = (const float*)d_in[4];
    const float* Wk  = (const float*)d_in[5];
    const float* Wv  = (const float*)d_in[6];
    const float* Wm  = (const float*)d_in[7];
    const float* W1  = (const float*)d_in[8];
    const float* W2  = (const float*)d_in[9];
    const float* g1  = (const float*)d_in[10];
    const float* b1  = (const float*)d_in[11];
    const float* g2  = (const float*)d_in[12];
    const float* b2  = (const float*)d_in[13];

    char* p = (char*)d_ws;
    unsigned short* WqT  = (unsigned short*)p; p += 256 * 256 * 2;
    unsigned short* WkvT = (unsigned short*)p; p += 512 * 256 * 2;
    unsigned short* WmT  = (unsigned short*)p; p += 256 * 256 * 2;
    unsigned short* W1T  = (unsigned short*)p; p += 512 * 512 * 2;
    unsigned short* W2T  = (unsigned short*)p; p += 256 * 512 * 2;
    float* KVT  = (float*)p; p += 64 * 1024 * 4;
    float* Ksum = (float*)p; p += 8 * 256 * 4;     // contiguous after KVT (zeroed together)
    float* Zbuf = (float*)p; p += (size_t)32768 * 8 * 4;
    unsigned short* A2   = (unsigned short*)p; p += (size_t)32768 * 512 * 2;  // cols 0-255: x, 256-511: LN1(msg)
    unsigned short* srcB = (unsigned short*)p; p += (size_t)32768 * 256 * 2;
    unsigned short* KF   = (unsigned short*)p; p += (size_t)32768 * 256 * 2;  // [nh][s/8][d][8]
    unsigned short* VF   = (unsigned short*)p; p += (size_t)32768 * 256 * 2;
    unsigned short* Qpos = (unsigned short*)p; p += (size_t)32768 * 256 * 2;
    unsigned short* Qrd  = (unsigned short*)p; p += (size_t)32768 * 256 * 2;
    unsigned short* hbuf = KF;   // 32MB over KF+VF (dead after kv2_kernel)

    // weights prep + KVT/Ksum zeroing: 655360 weight elems + 67584 zero floats = 2824 blocks
    prep_weights<<<2824, 256, 0, stream>>>(Wq, Wk, Wv, Wm, W1, W2,
                                           WqT, WkvT, WmT, W1T, W2T, KVT);
    conv_bf16<<<8192, 256, 0, stream>>>(x, A2, 512);
    conv_bf16<<<8192, 256, 0, stream>>>(src, srcB, 256);

    // K/V projection: rotary -> KF/VF frag layout, Ksum via atomics
    gemm_bt<128, 128, EPI_KV><<<dim3(256, 4), 256, 0, stream>>>(
        srcB, 256, WkvT, 256, nullptr, 0, spe, nullptr, Ksum,
        nullptr, nullptr, KF, VF, nullptr, nullptr, nullptr, nullptr, nullptr);
    kv2_kernel<<<dim3(64, 4), 256, 0, stream>>>(KF, VF, KVT);

    // Q projection: rotary + fused Z (Ksum ready)
    gemm_bt<128, 128, EPI_Q><<<dim3(256, 2), 256, 0, stream>>>(
        A2, 512, WqT, 256, nullptr, 0, xpe, Ksum, nullptr,
        Zbuf, Qpos, nullptr, nullptr, nullptr, nullptr, nullptr, nullptr, nullptr);

    attn_out_kernel<<<dim3(128, 8), 256, 0, stream>>>(Qpos, KVT, Zbuf, Qrd);

    // message = queried @ Wm -> LN1 -> A2 cols 256-511
    gemm_bt<64, 256, EPI_LN1><<<512, 256, 0, stream>>>(
        Qrd, 256, WmT, 256, nullptr, 0, nullptr, nullptr, nullptr,
        nullptr, nullptr, nullptr, nullptr, g1, b1, A2, nullptr, nullptr);

    // h = relu([x, message] @ W1)
    gemm_bt<128, 128, EPI_RELU><<<dim3(256, 4), 256, 0, stream>>>(
        A2, 512, W1T, 512, hbuf, 512, nullptr, nullptr, nullptr,
        nullptr, nullptr, nullptr, nullptr, nullptr, nullptr, nullptr, nullptr, nullptr);

    // out = x + LN2(h @ W2)
    gemm_bt<64, 256, EPI_LN2RES><<<512, 256, 0, stream>>>(
        hbuf, 512, W2T, 512, nullptr, 0, nullptr, nullptr, nullptr,
        nullptr, nullptr, nullptr, nullptr, g2, b2, nullptr, x, (float*)d_out);
}